// Round 3
// baseline (111.295 us; speedup 1.0000x reference)
//
#include <hip/hip_runtime.h>
#include <hip/hip_bf16.h>

#define NB 16
#define SQ 2048
#define SK 2048
#define DH 64

#define KBLK 1024      // prepass blocks for K convert
#define VBLK 512       // prepass blocks for V transpose
#define BBLK 128       // prepass blocks for bias

typedef __attribute__((ext_vector_type(8))) short short8;
typedef __attribute__((ext_vector_type(8))) __bf16 bf16x8;
typedef __attribute__((ext_vector_type(4))) float floatx4;
typedef __attribute__((ext_vector_type(16))) float floatx16;
typedef __attribute__((ext_vector_type(2))) unsigned uint2v;

#define GLOB const __attribute__((address_space(1))) void*
#define LDSP __attribute__((address_space(3))) void*

__device__ __forceinline__ unsigned pk2(float a, float b) {
  __hip_bfloat162 h = __float22bfloat162_rn(make_float2(a, b));
  unsigned u; __builtin_memcpy(&u, &h, 4); return u;
}
__device__ __forceinline__ floatx16 mfma32(short8 a, short8 b, floatx16 c) {
  return __builtin_amdgcn_mfma_f32_32x32x16_bf16(
      __builtin_bit_cast(bf16x8, a), __builtin_bit_cast(bf16x8, b), c, 0, 0, 0);
}

// K-tile key permutation: swap bits 2 and 3 of the row index.
__device__ __forceinline__ int swap23(int k) {
  return (((k >> 2) ^ (k >> 3)) & 1) ? (k ^ 12) : k;
}

// ---------- fused prepass: K (permuted) / V^T (natural) bf16 pre-swizzled tiles ----------
__global__ __launch_bounds__(256)
void prepass(const float* __restrict__ K, const float* __restrict__ V,
             const int* __restrict__ m, short* __restrict__ Kb,
             short* __restrict__ Vt, float* __restrict__ bias) {
  __shared__ unsigned tlw[64 * 33];   // [d][keypair], word-packed, +1 pad
  const int blk = blockIdx.x;
  const int t = threadIdx.x;
  if (blk < KBLK) {
    size_t i8 = ((size_t)blk * 256 + t) * 8;
    floatx4 a = *(const floatx4*)(K + i8);
    floatx4 b = *(const floatx4*)(K + i8 + 4);
    union { unsigned u[4]; short8 s; } w;
    w.u[0] = pk2(a[0], a[1]); w.u[1] = pk2(a[2], a[3]);
    w.u[2] = pk2(b[0], b[1]); w.u[3] = pk2(b[2], b[3]);
    const int local = (int)(i8 & 4095);
    const int key = local >> 6, chunk = (local >> 3) & 7;
    const int prow = swap23(key);                 // storage row for this key
    const size_t tb = i8 & ~(size_t)4095;
    *(short8*)(Kb + tb + prow * 64 + ((chunk ^ (prow & 7)) << 3)) = w.s;
  } else if (blk < KBLK + VBLK) {
    const int bt = blk - KBLK;            // b*32 + kt
    const int key2 = t & 31;              // key pair (NATURAL order)
    const int dg = (t >> 5) * 8;          // 0,8,...,56
    const float* vp0 = V + ((size_t)bt * 64 + 2 * key2) * 64 + dg;
    const float* vp1 = vp0 + 64;
    floatx4 va  = *(const floatx4*)(vp0);
    floatx4 va2 = *(const floatx4*)(vp0 + 4);
    floatx4 vb  = *(const floatx4*)(vp1);
    floatx4 vb2 = *(const floatx4*)(vp1 + 4);
#pragma unroll
    for (int j = 0; j < 4; ++j) {
      tlw[(dg + j) * 33 + key2]     = pk2(va[j],  vb[j]);
      tlw[(dg + 4 + j) * 33 + key2] = pk2(va2[j], vb2[j]);
    }
    __syncthreads();
    const short* tls = (const short*)tlw;
    short* dst = Vt + (size_t)bt * 4096;
#pragma unroll
    for (int i = 0; i < 2; ++i) {
      int idx = i * 2048 + t * 8;          // flat [d][key]; key multiple of 8
      int d = idx >> 6, key = idx & 63;
      int chunk = key >> 3;
      *(short8*)(dst + d * 64 + ((chunk ^ (d & 7)) << 3)) =
          *(const short8*)(tls + d * 66 + key);
    }
  } else {
    int i = (blk - KBLK - VBLK) * 256 + t;
    bias[i] = m[i] ? -1e30f : 0.0f;
  }
}

// ---------- main: NO split-K. 256 blocks (1/CU), each walks all 32 K/V tiles. ----------
// Counted-vmcnt DMA pipeline; in-kernel normalization; no partials, no combine.
__global__ __launch_bounds__(256, 1)
void attn_main(const float* __restrict__ Q, const short* __restrict__ Kb,
               const short* __restrict__ Vt, const float* __restrict__ bias,
               float* __restrict__ Out) {
  __shared__ __align__(16) short ks[2][4096];   // K tile, pre-swizzled + key-permuted
  __shared__ __align__(16) short vt[2][4096];   // V^T tile, pre-swizzled, natural order
  __shared__ __align__(16) float bsh[2048];     // full bias row for this b (32 tiles x 64)

  // XCD-aware decode (HW: xcd = blockIdx % 8). Each XCD serves 2 b-values:
  // working set = 2 x (512KB K/V bf16 + 512KB Q) ~ 2 MB < 4 MiB L2.
  const int gid = blockIdx.x;               // 0..255
  const int xcd = gid & 7;
  const int j   = gid >> 3;                 // 0..31
  const int b   = xcd + 8 * (j >> 4);       // 0..15
  const int qt  = j & 15;
  const int tid  = threadIdx.x;
  const int wave = tid >> 6;
  const int lane = tid & 63;
  const int n32  = lane & 31;     // this lane's query index
  const int h    = lane >> 5;     // lane half
  const int sw   = n32 & 7;       // swizzle key for rows read by this lane
  const int q0   = qt * 128 + wave * 32;

  // ---- Q B-fragments: qf[c] = Q[q0+n32][16c+8h .. +7], scale*(log2 e) folded ----
  const float QS = 0.125f * 1.4426950408889634f;
  short8 qf[4];
  {
    const float* qp = Q + ((size_t)b * SQ + q0 + n32) * DH + 8 * h;
#pragma unroll
    for (int c = 0; c < 4; ++c) {
      floatx4 a  = *(const floatx4*)(qp + 16 * c);
      floatx4 a2 = *(const floatx4*)(qp + 16 * c + 4);
      union { unsigned u[4]; short8 s; } w;
      w.u[0] = pk2(a[0] * QS, a[1] * QS);
      w.u[1] = pk2(a[2] * QS, a[3] * QS);
      w.u[2] = pk2(a2[0] * QS, a2[1] * QS);
      w.u[3] = pk2(a2[2] * QS, a2[3] * QS);
      qf[c] = w.s;
    }
  }

  // ---- stage full bias row into LDS once (8 KB) ----
  {
    const float* bp = bias + (size_t)b * SK + tid * 8;
    *(floatx4*)(bsh + tid * 8)     = *(const floatx4*)(bp);
    *(floatx4*)(bsh + tid * 8 + 4) = *(const floatx4*)(bp + 4);
  }

  floatx16 o0, o1;
#pragma unroll
  for (int i = 0; i < 16; ++i) { o0[i] = 0.f; o1[i] = 0.f; }
  float l_q = 0.f;

  const short* kg = Kb + (size_t)b * SK * DH;
  const short* vg = Vt + (size_t)b * 32 * 4096;

  // async staging: each wave DMAs 2x1KB per array; identity map (tiles pre-formatted)
  const int lo0 = (wave * 2) * 512;
  const int lo1 = (wave * 2 + 1) * 512;
  const int go0 = lo0 + lane * 8;
  const int go1 = lo1 + lane * 8;

#define ISSUE_K(tile, buf) do {                                                        \
    const short* kn_ = kg + (size_t)(tile) * 4096;                                     \
    __builtin_amdgcn_global_load_lds((GLOB)(kn_ + go0), (LDSP)&ks[buf][lo0], 16, 0, 0);\
    __builtin_amdgcn_global_load_lds((GLOB)(kn_ + go1), (LDSP)&ks[buf][lo1], 16, 0, 0);\
  } while (0)
#define ISSUE_V(tile, buf) do {                                                        \
    const short* vn_ = vg + (size_t)(tile) * 4096;                                     \
    __builtin_amdgcn_global_load_lds((GLOB)(vn_ + go0), (LDSP)&vt[buf][lo0], 16, 0, 0);\
    __builtin_amdgcn_global_load_lds((GLOB)(vn_ + go1), (LDSP)&vt[buf][lo1], 16, 0, 0);\
  } while (0)

  floatx16 sA[2], sB[2];

  // S^T = K Q^T for tile tt, accumulator initialized from LDS bias
#define QK(tt, d) do {                                                                 \
    const float* bq_ = bsh + (tt) * 64 + 8 * h;                                        \
    _Pragma("unroll") for (int u = 0; u < 4; ++u) {                                    \
      const int off_ = 16 * (u >> 1) + 4 * (u & 1);                                    \
      floatx4 bv0_ = *(const floatx4*)(bq_ + off_);                                    \
      floatx4 bv1_ = *(const floatx4*)(bq_ + 32 + off_);                               \
      _Pragma("unroll") for (int i = 0; i < 4; ++i) {                                  \
        sA[d][4 * u + i] = bv0_[i]; sB[d][4 * u + i] = bv1_[i]; } }                    \
    _Pragma("unroll") for (int c = 0; c < 4; ++c) {                                    \
      short8 kf0_ = *(short8*)(ks[(tt) & 1] + n32 * 64        + ((2 * c + h) ^ sw) * 8);\
      short8 kf1_ = *(short8*)(ks[(tt) & 1] + (32 + n32) * 64 + ((2 * c + h) ^ sw) * 8);\
      sA[d] = mfma32(kf0_, qf[c], sA[d]);                                              \
      sB[d] = mfma32(kf1_, qf[c], sB[d]); }                                            \
  } while (0)

  // ---- prologue: drain all prior VMEM so the vmcnt ledger is DMA-only ----
  asm volatile("s_waitcnt vmcnt(0) lgkmcnt(0)" ::: "memory");
  __builtin_amdgcn_sched_barrier(0);
  ISSUE_K(0, 0); ISSUE_V(0, 0); ISSUE_K(1, 1); ISSUE_V(1, 1);   // 8 loads in flight
  asm volatile("s_waitcnt vmcnt(6)" ::: "memory");               // K0 landed
  __builtin_amdgcn_s_barrier();                                  // bias + K0 visible
  __builtin_amdgcn_sched_barrier(0);
  QK(0, 0);                                                      // s(0)

#pragma unroll 2
  for (int t = 0; t < 32; ++t) {
    // entry: need V(t) and K(t+1) landed; V(t+1) may stay in flight.
    // in-flight here: {V(t), K(t+1), V(t+1)} = 6 loads (t<31), {V(31)} at t=31.
    if (t < 31) asm volatile("s_waitcnt vmcnt(2)" ::: "memory");
    else        asm volatile("s_waitcnt vmcnt(0)" ::: "memory");
    __builtin_amdgcn_s_barrier();          // all waves: tile data visible; QK(t) done
    __builtin_amdgcn_sched_barrier(0);

    if (t < 30) ISSUE_K(t + 2, t & 1);     // K(t) slot dead (QK(t) behind barrier)

    // ---- exp(t) [trans pipe] co-scheduled with QK(t+1) [MFMA pipe] ----
    uint2v pka[4], pkb[4];
    {
      float rs = 0.f;
#pragma unroll
      for (int u = 0; u < 4; ++u) {
        float p0 = __builtin_amdgcn_exp2f(sA[t & 1][4 * u + 0]);
        float p1 = __builtin_amdgcn_exp2f(sA[t & 1][4 * u + 1]);
        float p2 = __builtin_amdgcn_exp2f(sA[t & 1][4 * u + 2]);
        float p3 = __builtin_amdgcn_exp2f(sA[t & 1][4 * u + 3]);
        float r0 = __builtin_amdgcn_exp2f(sB[t & 1][4 * u + 0]);
        float r1 = __builtin_amdgcn_exp2f(sB[t & 1][4 * u + 1]);
        float r2 = __builtin_amdgcn_exp2f(sB[t & 1][4 * u + 2]);
        float r3 = __builtin_amdgcn_exp2f(sB[t & 1][4 * u + 3]);
        rs += ((p0 + p1) + (p2 + p3)) + ((r0 + r1) + (r2 + r3));
        pka[u].x = pk2(p0, p1); pka[u].y = pk2(p2, p3);
        pkb[u].x = pk2(r0, r1); pkb[u].y = pk2(r2, r3);
      }
      l_q += rs;
    }
    if (t < 31) QK(t + 1, (t + 1) & 1);    // reads ks[(t+1)&1]; rewrites freed s-set

    // ---- O^T += V^T P^T from vt[t&1] ----
#pragma unroll
    for (int c = 0; c < 4; ++c) {
      const uint2v* X = (c < 2) ? pka : pkb;
      union { unsigned u[4]; short8 s; } pf;
      pf.u[0] = X[2 * (c & 1)].x;     pf.u[1] = X[2 * (c & 1)].y;
      pf.u[2] = X[2 * (c & 1) + 1].x; pf.u[3] = X[2 * (c & 1) + 1].y;
      short8 vf0 = *(short8*)(vt[t & 1] + n32 * 64        + ((2 * c + h) ^ sw) * 8);
      short8 vf1 = *(short8*)(vt[t & 1] + (32 + n32) * 64 + ((2 * c + h) ^ sw) * 8);
      o0 = mfma32(vf0, pf.s, o0);
      o1 = mfma32(vf1, pf.s, o1);
    }

    if (t < 30) {
      __builtin_amdgcn_s_barrier();        // all waves' PV(t) reads done
      __builtin_amdgcn_sched_barrier(0);
      ISSUE_V(t + 2, t & 1);               // V(t) slot now safe to overwrite
    }
  }
#undef ISSUE_K
#undef ISSUE_V
#undef QK

  // ---- full-row softmax denominator -> normalize in-kernel, single output write ----
  l_q += __shfl_xor(l_q, 32);
  const float inv = 1.0f / l_q;

  float* orow = Out + ((size_t)b * SQ + q0 + n32) * DH;
#pragma unroll
  for (int u = 0; u < 4; ++u) {
    floatx4 w0, w1;
#pragma unroll
    for (int i = 0; i < 4; ++i) { w0[i] = o0[4 * u + i] * inv; w1[i] = o1[4 * u + i] * inv; }
    *(floatx4*)(orow + 8 * u + 4 * h)      = w0;
    *(floatx4*)(orow + 32 + 8 * u + 4 * h) = w1;
  }
}

extern "C" void kernel_launch(void* const* d_in, const int* in_sizes, int n_in,
                              void* d_out, int out_size, void* d_ws, size_t ws_size,
                              hipStream_t stream) {
  const float* Q = (const float*)d_in[0];
  const float* K = (const float*)d_in[1];
  const float* V = (const float*)d_in[2];
  const int* mask = (const int*)d_in[3];
  float* Out = (float*)d_out;

  char* ws = (char*)d_ws;
  short* Kb   = (short*)(ws);                           //  4 MB
  short* Vt   = (short*)(ws + 4194304);                 //  4 MB
  float* bias = (float*)(ws + 8388608);                 //  128 KB

  prepass  <<<KBLK + VBLK + BBLK, 256, 0, stream>>>(K, V, mask, Kb, Vt, bias);
  attn_main<<<NB * (SQ / 128), 256, 0, stream>>>(Q, Kb, Vt, bias, Out);
}

// Round 5
// 108.019 us; speedup vs baseline: 1.0303x; 1.0303x over previous
//
#include <hip/hip_runtime.h>
#include <hip/hip_bf16.h>

#define NB 16
#define SQ 2048
#define SK 2048
#define DH 64

#define KBLK 1024      // prepass blocks for K convert
#define VBLK 512       // prepass blocks for V transpose
#define BBLK 128       // prepass blocks for bias

#define NPART 2        // split-K parts
#define NT 16          // K-tiles per part

typedef __attribute__((ext_vector_type(8))) short short8;
typedef __attribute__((ext_vector_type(8))) __bf16 bf16x8;
typedef __attribute__((ext_vector_type(4))) float floatx4;
typedef __attribute__((ext_vector_type(16))) float floatx16;
typedef __attribute__((ext_vector_type(2))) unsigned uint2v;

#define GLOB const __attribute__((address_space(1))) void*
#define LDSP __attribute__((address_space(3))) void*

__device__ __forceinline__ unsigned pk2(float a, float b) {
  __hip_bfloat162 h = __float22bfloat162_rn(make_float2(a, b));
  unsigned u; __builtin_memcpy(&u, &h, 4); return u;
}
__device__ __forceinline__ floatx16 mfma32(short8 a, short8 b, floatx16 c) {
  return __builtin_amdgcn_mfma_f32_32x32x16_bf16(
      __builtin_bit_cast(bf16x8, a), __builtin_bit_cast(bf16x8, b), c, 0, 0, 0);
}

// K-tile key permutation: swap bits 2 and 3 of the row index.
__device__ __forceinline__ int swap23(int k) {
  return (((k >> 2) ^ (k >> 3)) & 1) ? (k ^ 12) : k;
}

// ---------- fused prepass: K (permuted) / V^T (natural) bf16 pre-swizzled tiles ----------
__global__ __launch_bounds__(256)
void prepass(const float* __restrict__ K, const float* __restrict__ V,
             const int* __restrict__ m, short* __restrict__ Kb,
             short* __restrict__ Vt, float* __restrict__ bias) {
  __shared__ unsigned tlw[64 * 33];   // [d][keypair], word-packed, +1 pad
  const int blk = blockIdx.x;
  const int t = threadIdx.x;
  if (blk < KBLK) {
    size_t i8 = ((size_t)blk * 256 + t) * 8;
    floatx4 a = *(const floatx4*)(K + i8);
    floatx4 b = *(const floatx4*)(K + i8 + 4);
    union { unsigned u[4]; short8 s; } w;
    w.u[0] = pk2(a[0], a[1]); w.u[1] = pk2(a[2], a[3]);
    w.u[2] = pk2(b[0], b[1]); w.u[3] = pk2(b[2], b[3]);
    const int local = (int)(i8 & 4095);
    const int key = local >> 6, chunk = (local >> 3) & 7;
    const int prow = swap23(key);                 // storage row for this key
    const size_t tb = i8 & ~(size_t)4095;
    *(short8*)(Kb + tb + prow * 64 + ((chunk ^ (prow & 7)) << 3)) = w.s;
  } else if (blk < KBLK + VBLK) {
    const int bt = blk - KBLK;            // b*32 + kt
    const int key2 = t & 31;              // key pair (NATURAL order)
    const int dg = (t >> 5) * 8;          // 0,8,...,56
    const float* vp0 = V + ((size_t)bt * 64 + 2 * key2) * 64 + dg;
    const float* vp1 = vp0 + 64;
    floatx4 va  = *(const floatx4*)(vp0);
    floatx4 va2 = *(const floatx4*)(vp0 + 4);
    floatx4 vb  = *(const floatx4*)(vp1);
    floatx4 vb2 = *(const floatx4*)(vp1 + 4);
#pragma unroll
    for (int j = 0; j < 4; ++j) {
      tlw[(dg + j) * 33 + key2]     = pk2(va[j],  vb[j]);
      tlw[(dg + 4 + j) * 33 + key2] = pk2(va2[j], vb2[j]);
    }
    __syncthreads();
    const short* tls = (const short*)tlw;
    short* dst = Vt + (size_t)bt * 4096;
#pragma unroll
    for (int i = 0; i < 2; ++i) {
      int idx = i * 2048 + t * 8;          // flat [d][key]; key multiple of 8
      int d = idx >> 6, key = idx & 63;
      int chunk = key >> 3;
      *(short8*)(dst + d * 64 + ((chunk ^ (d & 7)) << 3)) =
          *(const short8*)(tls + d * 66 + key);
    }
  } else {
    int i = (blk - KBLK - VBLK) * 256 + t;
    bias[i] = m[i] ? -1e30f : 0.0f;
  }
}

// ---------- main: split-K x2, 2 blocks/CU, counted-vmcnt pipeline, setprio MFMA ----------
__global__ __launch_bounds__(256, 2)
void attn_main(const float* __restrict__ Q, const short* __restrict__ Kb,
               const short* __restrict__ Vt, const float* __restrict__ bias,
               float* __restrict__ Out, float* __restrict__ Op,
               float* __restrict__ lsum) {
  __shared__ __align__(16) short ks[2][4096];   // K tile, pre-swizzled + key-permuted
  __shared__ __align__(16) short vt[2][4096];   // V^T tile, pre-swizzled, natural order
  __shared__ __align__(16) float bsh[1024];     // bias slice: NT tiles x 64 keys

  // XCD-aware decode (HW: xcd = blockIdx % 8). All 32 blocks (16 qt x 2 part)
  // of one b land on one XCD; 2 b per XCD -> ~2 MB working set, L2-resident.
  const int gid = blockIdx.x;               // 0..511
  const int xcd = gid & 7;
  const int j   = gid >> 3;                 // 0..63
  const int b   = xcd + 8 * (j >> 5);       // 0..15
  const int rem = j & 31;
  const int part = rem >> 4;                // 0..1
  const int qt   = rem & 15;
  const int tid  = threadIdx.x;
  const int wave = tid >> 6;
  const int lane = tid & 63;
  const int n32  = lane & 31;     // this lane's query index
  const int h    = lane >> 5;     // lane half
  const int sw   = n32 & 7;       // swizzle key for rows read by this lane
  const int q0   = qt * 128 + wave * 32;
  const int kt0  = part * NT;     // NT tiles per block

  // ---- Q B-fragments: qf[c] = Q[q0+n32][16c+8h .. +7], scale*(log2 e) folded ----
  const float QS = 0.125f * 1.4426950408889634f;
  short8 qf[4];
  {
    const float* qp = Q + ((size_t)b * SQ + q0 + n32) * DH + 8 * h;
#pragma unroll
    for (int c = 0; c < 4; ++c) {
      floatx4 a  = *(const floatx4*)(qp + 16 * c);
      floatx4 a2 = *(const floatx4*)(qp + 16 * c + 4);
      union { unsigned u[4]; short8 s; } w;
      w.u[0] = pk2(a[0] * QS, a[1] * QS);
      w.u[1] = pk2(a[2] * QS, a[3] * QS);
      w.u[2] = pk2(a2[0] * QS, a2[1] * QS);
      w.u[3] = pk2(a2[2] * QS, a2[3] * QS);
      qf[c] = w.s;
    }
  }

  // ---- stage bias slice (NT*64 = 1024 floats) into LDS once ----
  {
    floatx4 bv = *(const floatx4*)(bias + (size_t)b * SK + kt0 * 64 + tid * 4);
    *(floatx4*)(bsh + tid * 4) = bv;
  }

  floatx16 o0, o1;
#pragma unroll
  for (int i = 0; i < 16; ++i) { o0[i] = 0.f; o1[i] = 0.f; }
  float l_q = 0.f;

  const short* kg = Kb + ((size_t)b * SK + (size_t)kt0 * 64) * DH;
  const short* vg = Vt + ((size_t)b * 32 + kt0) * 4096;

  // async staging: each wave DMAs 2x1KB per array; identity map (tiles pre-formatted)
  const int lo0 = (wave * 2) * 512;
  const int lo1 = (wave * 2 + 1) * 512;
  const int go0 = lo0 + lane * 8;
  const int go1 = lo1 + lane * 8;

#define ISSUE_K(tile, buf) do {                                                        \
    const short* kn_ = kg + (size_t)(tile) * 4096;                                     \
    __builtin_amdgcn_global_load_lds((GLOB)(kn_ + go0), (LDSP)&ks[buf][lo0], 16, 0, 0);\
    __builtin_amdgcn_global_load_lds((GLOB)(kn_ + go1), (LDSP)&ks[buf][lo1], 16, 0, 0);\
  } while (0)
#define ISSUE_V(tile, buf) do {                                                        \
    const short* vn_ = vg + (size_t)(tile) * 4096;                                     \
    __builtin_amdgcn_global_load_lds((GLOB)(vn_ + go0), (LDSP)&vt[buf][lo0], 16, 0, 0);\
    __builtin_amdgcn_global_load_lds((GLOB)(vn_ + go1), (LDSP)&vt[buf][lo1], 16, 0, 0);\
  } while (0)

  floatx16 sA[2], sB[2];

  // S^T = K Q^T for tile tt, accumulator initialized from LDS bias
#define QK(tt, d) do {                                                                 \
    const float* bq_ = bsh + (tt) * 64 + 8 * h;                                        \
    _Pragma("unroll") for (int u = 0; u < 4; ++u) {                                    \
      const int off_ = 16 * (u >> 1) + 4 * (u & 1);                                    \
      floatx4 bv0_ = *(const floatx4*)(bq_ + off_);                                    \
      floatx4 bv1_ = *(const floatx4*)(bq_ + 32 + off_);                               \
      _Pragma("unroll") for (int i = 0; i < 4; ++i) {                                  \
        sA[d][4 * u + i] = bv0_[i]; sB[d][4 * u + i] = bv1_[i]; } }                    \
    __builtin_amdgcn_s_setprio(1);                                                     \
    _Pragma("unroll") for (int c = 0; c < 4; ++c) {                                    \
      short8 kf0_ = *(short8*)(ks[(tt) & 1] + n32 * 64        + ((2 * c + h) ^ sw) * 8);\
      short8 kf1_ = *(short8*)(ks[(tt) & 1] + (32 + n32) * 64 + ((2 * c + h) ^ sw) * 8);\
      sA[d] = mfma32(kf0_, qf[c], sA[d]);                                              \
      sB[d] = mfma32(kf1_, qf[c], sB[d]); }                                            \
    __builtin_amdgcn_s_setprio(0);                                                     \
  } while (0)

  // ---- prologue: drain all prior VMEM so the vmcnt ledger is DMA-only ----
  asm volatile("s_waitcnt vmcnt(0) lgkmcnt(0)" ::: "memory");
  __builtin_amdgcn_sched_barrier(0);
  ISSUE_K(0, 0); ISSUE_V(0, 0); ISSUE_K(1, 1); ISSUE_V(1, 1);   // 8 loads in flight
  asm volatile("s_waitcnt vmcnt(6)" ::: "memory");               // K0 landed
  __builtin_amdgcn_s_barrier();                                  // bias + K0 visible
  __builtin_amdgcn_sched_barrier(0);
  QK(0, 0);                                                      // s(0)

#pragma unroll 2
  for (int t = 0; t < NT; ++t) {
    // entry: need V(t) and K(t+1) landed; V(t+1) may stay in flight.
    // in-flight here: {V(t), K(t+1), V(t+1)} = 6 loads (t<NT-1), {V(NT-1)} at last.
    if (t < NT - 1) asm volatile("s_waitcnt vmcnt(2)" ::: "memory");
    else            asm volatile("s_waitcnt vmcnt(0)" ::: "memory");
    __builtin_amdgcn_s_barrier();          // all waves: tile data visible; QK(t) done
    __builtin_amdgcn_sched_barrier(0);

    if (t < NT - 2) ISSUE_K(t + 2, t & 1); // K(t) slot dead (QK(t) behind barrier)

    // ---- exp(t) [trans pipe] co-scheduled with QK(t+1) [MFMA pipe] ----
    uint2v pka[4], pkb[4];
    {
      float rs = 0.f;
#pragma unroll
      for (int u = 0; u < 4; ++u) {
        float p0 = __builtin_amdgcn_exp2f(sA[t & 1][4 * u + 0]);
        float p1 = __builtin_amdgcn_exp2f(sA[t & 1][4 * u + 1]);
        float p2 = __builtin_amdgcn_exp2f(sA[t & 1][4 * u + 2]);
        float p3 = __builtin_amdgcn_exp2f(sA[t & 1][4 * u + 3]);
        float r0 = __builtin_amdgcn_exp2f(sB[t & 1][4 * u + 0]);
        float r1 = __builtin_amdgcn_exp2f(sB[t & 1][4 * u + 1]);
        float r2 = __builtin_amdgcn_exp2f(sB[t & 1][4 * u + 2]);
        float r3 = __builtin_amdgcn_exp2f(sB[t & 1][4 * u + 3]);
        rs += ((p0 + p1) + (p2 + p3)) + ((r0 + r1) + (r2 + r3));
        pka[u].x = pk2(p0, p1); pka[u].y = pk2(p2, p3);
        pkb[u].x = pk2(r0, r1); pkb[u].y = pk2(r2, r3);
      }
      l_q += rs;
    }
    if (t < NT - 1) QK(t + 1, (t + 1) & 1); // reads ks[(t+1)&1]; rewrites freed s-set

    // ---- O^T += V^T P^T from vt[t&1] ----
    __builtin_amdgcn_s_setprio(1);
#pragma unroll
    for (int c = 0; c < 4; ++c) {
      const uint2v* X = (c < 2) ? pka : pkb;
      union { unsigned u[4]; short8 s; } pf;
      pf.u[0] = X[2 * (c & 1)].x;     pf.u[1] = X[2 * (c & 1)].y;
      pf.u[2] = X[2 * (c & 1) + 1].x; pf.u[3] = X[2 * (c & 1) + 1].y;
      short8 vf0 = *(short8*)(vt[t & 1] + n32 * 64        + ((2 * c + h) ^ sw) * 8);
      short8 vf1 = *(short8*)(vt[t & 1] + (32 + n32) * 64 + ((2 * c + h) ^ sw) * 8);
      o0 = mfma32(vf0, pf.s, o0);
      o1 = mfma32(vf1, pf.s, o1);
    }
    __builtin_amdgcn_s_setprio(0);

    if (t < NT - 2) {
      __builtin_amdgcn_s_barrier();        // all waves' PV(t) reads done
      __builtin_amdgcn_sched_barrier(0);
      ISSUE_V(t + 2, t & 1);               // V(t) slot now safe to overwrite
    }
  }
#undef ISSUE_K
#undef ISSUE_V
#undef QK

  l_q += __shfl_xor(l_q, 32);

  // ---- epilogue: unnormalized partial O + l ----
  float* Od = part ? Op : Out;
  float* orow = Od + ((size_t)b * SQ + q0 + n32) * DH;
#pragma unroll
  for (int u = 0; u < 4; ++u) {
    floatx4 w0, w1;
#pragma unroll
    for (int i = 0; i < 4; ++i) { w0[i] = o0[4 * u + i]; w1[i] = o1[4 * u + i]; }
    *(floatx4*)(orow + 8 * u + 4 * h)      = w0;
    *(floatx4*)(orow + 32 + 8 * u + 4 * h) = w1;
  }
  if (lane < 32)
    lsum[(size_t)part * NB * SQ + (size_t)b * SQ + q0 + lane] = l_q;
}

// ---------- combine the two split-K parts (no max needed) ----------
__global__ __launch_bounds__(256)
void combine(const float* __restrict__ Op, const float* __restrict__ lsum,
             float* __restrict__ Out) {
  int idx = blockIdx.x * 256 + threadIdx.x;
  int q = idx >> 3;
  int dc = (idx & 7) * 8;
  float inv = 1.0f / (lsum[q] + lsum[NB * SQ + q]);
  const size_t base = (size_t)q * DH + dc;
  floatx4 a0 = *(const floatx4*)(Out + base);
  floatx4 a1 = *(const floatx4*)(Out + base + 4);
  floatx4 b0 = *(const floatx4*)(Op + base);
  floatx4 b1 = *(const floatx4*)(Op + base + 4);
  *(floatx4*)(Out + base)     = (a0 + b0) * inv;
  *(floatx4*)(Out + base + 4) = (a1 + b1) * inv;
}

extern "C" void kernel_launch(void* const* d_in, const int* in_sizes, int n_in,
                              void* d_out, int out_size, void* d_ws, size_t ws_size,
                              hipStream_t stream) {
  const float* Q = (const float*)d_in[0];
  const float* K = (const float*)d_in[1];
  const float* V = (const float*)d_in[2];
  const int* mask = (const int*)d_in[3];
  float* Out = (float*)d_out;

  char* ws = (char*)d_ws;
  short* Kb   = (short*)(ws);                           //  4 MB
  short* Vt   = (short*)(ws + 4194304);                 //  4 MB
  float* bias = (float*)(ws + 8388608);                 //  128 KB
  float* lsum = (float*)(ws + 8519680);                 //  256 KB (2 parts)
  float* Op   = (float*)(ws + 8781824);                 //  8 MB (part-1 partial)

  prepass  <<<KBLK + VBLK + BBLK, 256, 0, stream>>>(K, V, mask, Kb, Vt, bias);
  attn_main<<<NPART * NB * (SQ / 128), 256, 0, stream>>>(Q, Kb, Vt, bias, Out, Op, lsum);
  combine  <<<NB * SQ * DH / 8 / 256, 256, 0, stream>>>(Op, lsum, Out);
}

// Round 7
// 104.533 us; speedup vs baseline: 1.0647x; 1.0333x over previous
//
#include <hip/hip_runtime.h>
#include <hip/hip_bf16.h>

#define NB 16
#define SQ 2048
#define SK 2048
#define DH 64

#define KBLK 1024      // prepass blocks for K convert
#define VBLK 512       // prepass blocks for V transpose
#define BBLK 128       // prepass blocks for bias

#define NT 16          // K-tiles per wave-pair (2 pairs cover 32)

typedef __attribute__((ext_vector_type(8))) short short8;
typedef __attribute__((ext_vector_type(8))) __bf16 bf16x8;
typedef __attribute__((ext_vector_type(4))) float floatx4;
typedef __attribute__((ext_vector_type(16))) float floatx16;
typedef __attribute__((ext_vector_type(2))) unsigned uint2v;

#define GLOB const __attribute__((address_space(1))) void*
#define LDSP __attribute__((address_space(3))) void*

__device__ __forceinline__ unsigned pk2(float a, float b) {
  __hip_bfloat162 h = __float22bfloat162_rn(make_float2(a, b));
  unsigned u; __builtin_memcpy(&u, &h, 4); return u;
}
__device__ __forceinline__ floatx16 mfma32(short8 a, short8 b, floatx16 c) {
  return __builtin_amdgcn_mfma_f32_32x32x16_bf16(
      __builtin_bit_cast(bf16x8, a), __builtin_bit_cast(bf16x8, b), c, 0, 0, 0);
}

// K-tile key permutation: swap bits 2 and 3 of the row index.
__device__ __forceinline__ int swap23(int k) {
  return (((k >> 2) ^ (k >> 3)) & 1) ? (k ^ 12) : k;
}

// ---------- fused prepass: K (permuted) / V^T (natural) bf16 pre-swizzled tiles ----------
__global__ __launch_bounds__(256)
void prepass(const float* __restrict__ K, const float* __restrict__ V,
             const int* __restrict__ m, short* __restrict__ Kb,
             short* __restrict__ Vt, float* __restrict__ bias) {
  __shared__ unsigned tlw[64 * 33];   // [d][keypair], word-packed, +1 pad
  const int blk = blockIdx.x;
  const int t = threadIdx.x;
  if (blk < KBLK) {
    size_t i8 = ((size_t)blk * 256 + t) * 8;
    floatx4 a = *(const floatx4*)(K + i8);
    floatx4 b = *(const floatx4*)(K + i8 + 4);
    union { unsigned u[4]; short8 s; } w;
    w.u[0] = pk2(a[0], a[1]); w.u[1] = pk2(a[2], a[3]);
    w.u[2] = pk2(b[0], b[1]); w.u[3] = pk2(b[2], b[3]);
    const int local = (int)(i8 & 4095);
    const int key = local >> 6, chunk = (local >> 3) & 7;
    const int prow = swap23(key);                 // storage row for this key
    const size_t tb = i8 & ~(size_t)4095;
    *(short8*)(Kb + tb + prow * 64 + ((chunk ^ (prow & 7)) << 3)) = w.s;
  } else if (blk < KBLK + VBLK) {
    const int bt = blk - KBLK;            // b*32 + kt
    const int key2 = t & 31;              // key pair (NATURAL order)
    const int dg = (t >> 5) * 8;          // 0,8,...,56
    const float* vp0 = V + ((size_t)bt * 64 + 2 * key2) * 64 + dg;
    const float* vp1 = vp0 + 64;
    floatx4 va  = *(const floatx4*)(vp0);
    floatx4 va2 = *(const floatx4*)(vp0 + 4);
    floatx4 vb  = *(const floatx4*)(vp1);
    floatx4 vb2 = *(const floatx4*)(vp1 + 4);
#pragma unroll
    for (int j = 0; j < 4; ++j) {
      tlw[(dg + j) * 33 + key2]     = pk2(va[j],  vb[j]);
      tlw[(dg + 4 + j) * 33 + key2] = pk2(va2[j], vb2[j]);
    }
    __syncthreads();
    const short* tls = (const short*)tlw;
    short* dst = Vt + (size_t)bt * 4096;
#pragma unroll
    for (int i = 0; i < 2; ++i) {
      int idx = i * 2048 + t * 8;          // flat [d][key]; key multiple of 8
      int d = idx >> 6, key = idx & 63;
      int chunk = key >> 3;
      *(short8*)(dst + d * 64 + ((chunk ^ (d & 7)) << 3)) =
          *(const short8*)(tls + d * 66 + key);
    }
  } else {
    int i = (blk - KBLK - VBLK) * 256 + t;
    bias[i] = m[i] ? -1e30f : 0.0f;
  }
}

// ---------- main: intra-block split-K x2 (wave pairs), single kernel, no partials ----------
// Block = 64 q-rows. Pair pr=wave>>1 handles K-tiles [pr*16, pr*16+16).
// Pair-1 accumulators are combined with pair-0's through LDS at the end; Out
// is written once, normalized. No inter-block communication anywhere.
__global__ __launch_bounds__(256, 2)
void attn_main(const float* __restrict__ Q, const short* __restrict__ Kb,
               const short* __restrict__ Vt, const float* __restrict__ bias,
               float* __restrict__ Out) {
  __shared__ __align__(16) short ksp[2][2][4096];  // [pair][dbuf] K tile (32 KB)
  __shared__ __align__(16) short vtp[2][2][4096];  // [pair][dbuf] V^T tile (32 KB)
  __shared__ __align__(16) float bsh[2048];        // full bias row: 32 tiles x 64 (8 KB)

  // XCD-aware decode (HW: xcd = blockIdx % 8). All 32 qt-blocks of one b land
  // on one XCD; 2 b per XCD -> ~2 MB K/V+Q working set, L2-resident.
  const int gid = blockIdx.x;               // 0..511
  const int xcd = gid & 7;
  const int j   = gid >> 3;                 // 0..63
  const int b   = xcd + 8 * (j >> 5);       // 0..15
  const int qt  = j & 31;                   // 0..31 (64-row tiles)
  const int tid  = threadIdx.x;
  const int wave = tid >> 6;
  const int lane = tid & 63;
  const int wp   = wave & 1;      // which 32-row half of the block
  const int pr   = wave >> 1;     // K-part (0: tiles 0..15, 1: tiles 16..31)
  const int n32  = lane & 31;     // this lane's query index
  const int h    = lane >> 5;     // lane half
  const int sw   = n32 & 7;       // swizzle key for rows read by this lane
  const int q0   = qt * 64 + wp * 32;
  const int kt0  = pr * NT;

  // ---- Q B-fragments: qf[c] = Q[q0+n32][16c+8h .. +7], scale*(log2 e) folded ----
  const float QS = 0.125f * 1.4426950408889634f;
  short8 qf[4];
  {
    const float* qp = Q + ((size_t)b * SQ + q0 + n32) * DH + 8 * h;
#pragma unroll
    for (int c = 0; c < 4; ++c) {
      floatx4 a  = *(const floatx4*)(qp + 16 * c);
      floatx4 a2 = *(const floatx4*)(qp + 16 * c + 4);
      union { unsigned u[4]; short8 s; } w;
      w.u[0] = pk2(a[0] * QS, a[1] * QS);
      w.u[1] = pk2(a[2] * QS, a[3] * QS);
      w.u[2] = pk2(a2[0] * QS, a2[1] * QS);
      w.u[3] = pk2(a2[2] * QS, a2[3] * QS);
      qf[c] = w.s;
    }
  }

  // ---- stage full bias row (2048 floats) into LDS once ----
  {
    const float* bp = bias + (size_t)b * SK + tid * 8;
    *(floatx4*)(bsh + tid * 8)     = *(const floatx4*)(bp);
    *(floatx4*)(bsh + tid * 8 + 4) = *(const floatx4*)(bp + 4);
  }

  floatx16 o0, o1;
#pragma unroll
  for (int i = 0; i < 16; ++i) { o0[i] = 0.f; o1[i] = 0.f; }
  float l_q = 0.f;

  const short* kg = Kb + ((size_t)b * SK + (size_t)kt0 * 64) * DH;
  const short* vg = Vt + ((size_t)b * 32 + kt0) * 4096;

  // async staging: each PAIR owns its tile; each wave DMAs 4x1KB per array.
  // LDS dest is wave-uniform base; global src carries the lane offset.
#define ISSUE_K(tile, buf) do {                                                          \
    const short* kn_ = kg + (size_t)(tile) * 4096 + wp * 2048;                           \
    short* ld_ = &ksp[pr][buf][wp * 2048];                                               \
    __builtin_amdgcn_global_load_lds((GLOB)(kn_ + lane * 8),        (LDSP)(ld_),        16, 0, 0);\
    __builtin_amdgcn_global_load_lds((GLOB)(kn_ + 512 + lane * 8),  (LDSP)(ld_ + 512),  16, 0, 0);\
    __builtin_amdgcn_global_load_lds((GLOB)(kn_ + 1024 + lane * 8), (LDSP)(ld_ + 1024), 16, 0, 0);\
    __builtin_amdgcn_global_load_lds((GLOB)(kn_ + 1536 + lane * 8), (LDSP)(ld_ + 1536), 16, 0, 0);\
  } while (0)
#define ISSUE_V(tile, buf) do {                                                          \
    const short* vn_ = vg + (size_t)(tile) * 4096 + wp * 2048;                           \
    short* ld_ = &vtp[pr][buf][wp * 2048];                                               \
    __builtin_amdgcn_global_load_lds((GLOB)(vn_ + lane * 8),        (LDSP)(ld_),        16, 0, 0);\
    __builtin_amdgcn_global_load_lds((GLOB)(vn_ + 512 + lane * 8),  (LDSP)(ld_ + 512),  16, 0, 0);\
    __builtin_amdgcn_global_load_lds((GLOB)(vn_ + 1024 + lane * 8), (LDSP)(ld_ + 1024), 16, 0, 0);\
    __builtin_amdgcn_global_load_lds((GLOB)(vn_ + 1536 + lane * 8), (LDSP)(ld_ + 1536), 16, 0, 0);\
  } while (0)

  floatx16 sA[2], sB[2];

  // S^T = K Q^T for pair-local tile tt, accumulator initialized from LDS bias
#define QK(tt, d) do {                                                                   \
    const float* bq_ = bsh + (kt0 + (tt)) * 64 + 8 * h;                                  \
    _Pragma("unroll") for (int u = 0; u < 4; ++u) {                                      \
      const int off_ = 16 * (u >> 1) + 4 * (u & 1);                                      \
      floatx4 bv0_ = *(const floatx4*)(bq_ + off_);                                      \
      floatx4 bv1_ = *(const floatx4*)(bq_ + 32 + off_);                                 \
      _Pragma("unroll") for (int i = 0; i < 4; ++i) {                                    \
        sA[d][4 * u + i] = bv0_[i]; sB[d][4 * u + i] = bv1_[i]; } }                      \
    __builtin_amdgcn_s_setprio(1);                                                       \
    _Pragma("unroll") for (int c = 0; c < 4; ++c) {                                      \
      short8 kf0_ = *(short8*)(ksp[pr][(tt) & 1] + n32 * 64        + ((2 * c + h) ^ sw) * 8);\
      short8 kf1_ = *(short8*)(ksp[pr][(tt) & 1] + (32 + n32) * 64 + ((2 * c + h) ^ sw) * 8);\
      sA[d] = mfma32(kf0_, qf[c], sA[d]);                                                \
      sB[d] = mfma32(kf1_, qf[c], sB[d]); }                                              \
    __builtin_amdgcn_s_setprio(0);                                                       \
  } while (0)

  // ---- prologue: drain all prior VMEM so the vmcnt ledger is DMA-only ----
  asm volatile("s_waitcnt vmcnt(0) lgkmcnt(0)" ::: "memory");
  __builtin_amdgcn_sched_barrier(0);
  ISSUE_K(0, 0); ISSUE_V(0, 0); ISSUE_K(1, 1); ISSUE_V(1, 1);   // 16 loads in flight
  asm volatile("s_waitcnt vmcnt(12)" ::: "memory");              // K0 landed
  __builtin_amdgcn_s_barrier();                                  // bias + K0 visible
  __builtin_amdgcn_sched_barrier(0);
  QK(0, 0);                                                      // s(0)

#pragma unroll 2
  for (int t = 0; t < NT; ++t) {
    // entry: need V(t) and K(t+1) landed; V(t+1) (4 loads) may stay in flight.
    // in-flight here: {V(t), K(t+1), V(t+1)} = 12 loads (t<NT-1), {V(NT-1)}=4 at last.
    if (t < NT - 1) asm volatile("s_waitcnt vmcnt(4)" ::: "memory");
    else            asm volatile("s_waitcnt vmcnt(0)" ::: "memory");
    __builtin_amdgcn_s_barrier();          // all waves: tile data visible; QK(t) done
    __builtin_amdgcn_sched_barrier(0);

    if (t < NT - 2) ISSUE_K(t + 2, t & 1); // K(t) slot dead (QK(t) behind barrier)

    // ---- exp(t) [trans pipe] co-scheduled with QK(t+1) [MFMA pipe] ----
    uint2v pka[4], pkb[4];
    {
      float rs = 0.f;
#pragma unroll
      for (int u = 0; u < 4; ++u) {
        float p0 = __builtin_amdgcn_exp2f(sA[t & 1][4 * u + 0]);
        float p1 = __builtin_amdgcn_exp2f(sA[t & 1][4 * u + 1]);
        float p2 = __builtin_amdgcn_exp2f(sA[t & 1][4 * u + 2]);
        float p3 = __builtin_amdgcn_exp2f(sA[t & 1][4 * u + 3]);
        float r0 = __builtin_amdgcn_exp2f(sB[t & 1][4 * u + 0]);
        float r1 = __builtin_amdgcn_exp2f(sB[t & 1][4 * u + 1]);
        float r2 = __builtin_amdgcn_exp2f(sB[t & 1][4 * u + 2]);
        float r3 = __builtin_amdgcn_exp2f(sB[t & 1][4 * u + 3]);
        rs += ((p0 + p1) + (p2 + p3)) + ((r0 + r1) + (r2 + r3));
        pka[u].x = pk2(p0, p1); pka[u].y = pk2(p2, p3);
        pkb[u].x = pk2(r0, r1); pkb[u].y = pk2(r2, r3);
      }
      l_q += rs;
    }
    if (t < NT - 1) QK(t + 1, (t + 1) & 1); // reads ksp[pr][(t+1)&1]; rewrites freed s-set

    // ---- O^T += V^T P^T from vtp[pr][t&1] ----
    __builtin_amdgcn_s_setprio(1);
#pragma unroll
    for (int c = 0; c < 4; ++c) {
      const uint2v* X = (c < 2) ? pka : pkb;
      union { unsigned u[4]; short8 s; } pf;
      pf.u[0] = X[2 * (c & 1)].x;     pf.u[1] = X[2 * (c & 1)].y;
      pf.u[2] = X[2 * (c & 1) + 1].x; pf.u[3] = X[2 * (c & 1) + 1].y;
      short8 vf0 = *(short8*)(vtp[pr][t & 1] + n32 * 64        + ((2 * c + h) ^ sw) * 8);
      short8 vf1 = *(short8*)(vtp[pr][t & 1] + (32 + n32) * 64 + ((2 * c + h) ^ sw) * 8);
      o0 = mfma32(vf0, pf.s, o0);
      o1 = mfma32(vf1, pf.s, o1);
    }
    __builtin_amdgcn_s_setprio(0);

    if (t < NT - 2) {
      __builtin_amdgcn_s_barrier();        // all waves' PV(t) reads done
      __builtin_amdgcn_sched_barrier(0);
      ISSUE_V(t + 2, t & 1);               // V(t) slot now safe to overwrite
    }
  }
#undef ISSUE_K
#undef ISSUE_V
#undef QK

  l_q += __shfl_xor(l_q, 32);

  // ---- intra-block combine of the two K-parts through (now dead) LDS ----
  __syncthreads();                          // all tile reads done; LDS reusable
  float* Xs = (float*)&ksp[0][0][0];        // 8192 floats available; need 4096
  float* Ls = (float*)&vtp[0][0][0];
  if (pr == 1) {
#pragma unroll
    for (int e = 0; e < 16; ++e) {
      Xs[e * 128 + wp * 64 + lane]        = o0[e];   // [e][lane]: conflict-free
      Xs[(16 + e) * 128 + wp * 64 + lane] = o1[e];
    }
    Ls[wp * 64 + lane] = l_q;
  }
  __syncthreads();
  if (pr == 0) {
#pragma unroll
    for (int e = 0; e < 16; ++e) {
      o0[e] += Xs[e * 128 + wp * 64 + lane];
      o1[e] += Xs[(16 + e) * 128 + wp * 64 + lane];
    }
    const float inv = 1.0f / (l_q + Ls[wp * 64 + lane]);
    float* orow = Out + ((size_t)b * SQ + q0 + n32) * DH;
#pragma unroll
    for (int u = 0; u < 4; ++u) {
      floatx4 w0, w1;
#pragma unroll
      for (int i = 0; i < 4; ++i) { w0[i] = o0[4 * u + i] * inv; w1[i] = o1[4 * u + i] * inv; }
      *(floatx4*)(orow + 8 * u + 4 * h)      = w0;
      *(floatx4*)(orow + 32 + 8 * u + 4 * h) = w1;
    }
  }
}

extern "C" void kernel_launch(void* const* d_in, const int* in_sizes, int n_in,
                              void* d_out, int out_size, void* d_ws, size_t ws_size,
                              hipStream_t stream) {
  const float* Q = (const float*)d_in[0];
  const float* K = (const float*)d_in[1];
  const float* V = (const float*)d_in[2];
  const int* mask = (const int*)d_in[3];
  float* Out = (float*)d_out;

  char* ws = (char*)d_ws;
  short* Kb   = (short*)(ws);                           //  4 MB
  short* Vt   = (short*)(ws + 4194304);                 //  4 MB
  float* bias = (float*)(ws + 8388608);                 //  128 KB

  prepass  <<<KBLK + VBLK + BBLK, 256, 0, stream>>>(K, V, mask, Kb, Vt, bias);
  attn_main<<<NB * (SQ / 64), 256, 0, stream>>>(Q, Kb, Vt, bias, Out);
}